// Round 8
// baseline (297.565 us; speedup 1.0000x reference)
//
#include <hip/hip_runtime.h>
#include <hip/hip_bf16.h>

#define BB 8
#define TT 2048
#define DD 512
#define SQRTD 22.62741699796952f

typedef float fv4 __attribute__((ext_vector_type(4)));
typedef short bv8 __attribute__((ext_vector_type(8)));
typedef short bv4 __attribute__((ext_vector_type(4)));
typedef int iv2 __attribute__((ext_vector_type(2)));

__device__ __forceinline__ short f2bf(float f) {
  __hip_bfloat16 h = __float2bfloat16(f);
  return *reinterpret_cast<short*>(&h);
}
__device__ __forceinline__ float bf2f(short s) {
  union { unsigned u; float f; } a; a.u = ((unsigned)(unsigned short)s) << 16;
  return a.f;
}

__device__ __forceinline__ void gld_lds16(const void* g, void* l) {
  __builtin_amdgcn_global_load_lds(
      (const __attribute__((address_space(1))) void*)g,
      (__attribute__((address_space(3))) void*)l, 16, 0, 0);
}

// ---------------- K1: fused projection GEMM: C = X @ W^T (f32 in, bf16 out)
__global__ __launch_bounds__(256, 2) void k_proj(
    const float* __restrict__ Xq, const float* __restrict__ Xk, const float* __restrict__ Xv,
    const float* __restrict__ Wq, const float* __restrict__ Wk, const float* __restrict__ Wv,
    short* __restrict__ Qb, short* __restrict__ Kb, short* __restrict__ Vb)
{
  __shared__ short At[128 * 64];
  __shared__ short Bt[128 * 64];
  const int z = blockIdx.z;
  const float* __restrict__ X = (z == 0) ? Xq : (z == 1) ? Xk : Xv;
  const float* __restrict__ W = (z == 0) ? Wq : (z == 1) ? Wk : Wv;
  short* __restrict__ C = (z == 0) ? Qb : (z == 1) ? Kb : Vb;
  const int m0 = blockIdx.x * 128;
  const int n0 = blockIdx.y * 128;
  const int t = threadIdx.x;
  const int lane = t & 63;
  const int w = t >> 6;
  const int wr = (w >> 1) * 64, wc = (w & 1) * 64;
  fv4 acc[4][4] = {};
  for (int kt = 0; kt < DD; kt += 64) {
    #pragma unroll
    for (int j = 0; j < 8; ++j) {
      int f = j * 256 + t;
      int row = f >> 4, c4 = f & 15;
      int byte = (row * 128 + c4 * 8) ^ ((row & 7) << 4);
      fv4 va = *(const fv4*)(X + (size_t)(m0 + row) * DD + kt + c4 * 4);
      bv4 ha;
      #pragma unroll
      for (int e = 0; e < 4; ++e) ha[e] = f2bf(va[e]);
      *(bv4*)((char*)At + byte) = ha;
      fv4 vb = *(const fv4*)(W + (size_t)(n0 + row) * DD + kt + c4 * 4);
      bv4 hb;
      #pragma unroll
      for (int e = 0; e < 4; ++e) hb[e] = f2bf(vb[e]);
      *(bv4*)((char*)Bt + byte) = hb;
    }
    __syncthreads();
    #pragma unroll
    for (int ks = 0; ks < 2; ++ks) {
      bv8 af[4], bfr[4];
      #pragma unroll
      for (int i = 0; i < 4; ++i) {
        int ra = wr + i * 16 + (lane & 15);
        af[i] = *(bv8*)((char*)At + ((ra * 128 + ks * 64 + ((lane >> 4) * 16)) ^ ((ra & 7) << 4)));
        int rb = wc + i * 16 + (lane & 15);
        bfr[i] = *(bv8*)((char*)Bt + ((rb * 128 + ks * 64 + ((lane >> 4) * 16)) ^ ((rb & 7) << 4)));
      }
      #pragma unroll
      for (int mi = 0; mi < 4; ++mi)
        #pragma unroll
        for (int ni = 0; ni < 4; ++ni)
          acc[mi][ni] = __builtin_amdgcn_mfma_f32_16x16x32_bf16(af[mi], bfr[ni], acc[mi][ni], 0, 0, 0);
    }
    __syncthreads();
  }
  #pragma unroll
  for (int mi = 0; mi < 4; ++mi)
    #pragma unroll
    for (int r = 0; r < 4; ++r) {
      int gm = m0 + wr + mi * 16 + ((lane >> 4) << 2) + r;
      #pragma unroll
      for (int ni = 0; ni < 4; ++ni) {
        int gn = n0 + wc + ni * 16 + (lane & 15);
        C[(size_t)gm * DD + gn] = f2bf(acc[mi][ni][r]);
      }
    }
}

// ---------------- K1b: transpose V (B,T,D) -> Vt (B,D,T), bf16
__global__ __launch_bounds__(256) void k_transpose(
    const short* __restrict__ Vb, short* __restrict__ Vt)
{
  __shared__ short tile[64][72];
  const int b = blockIdx.z;
  const int t0 = blockIdx.x * 64;
  const int d0 = blockIdx.y * 64;
  const int t = threadIdx.x;
  #pragma unroll
  for (int j = 0; j < 2; ++j) {
    int f = j * 256 + t;
    int row = f >> 3, c8 = f & 7;
    bv8 v = *(const bv8*)(Vb + ((size_t)b * TT + t0 + row) * DD + d0 + c8 * 8);
    *(bv8*)&tile[row][c8 * 8] = v;
  }
  __syncthreads();
  #pragma unroll
  for (int j = 0; j < 2; ++j) {
    int f = j * 256 + t;
    int drow = f >> 3, c8 = f & 7;
    bv8 v;
    #pragma unroll
    for (int e = 0; e < 8; ++e) v[e] = tile[c8 * 8 + e][drow];
    *(bv8*)(Vt + ((size_t)b * DD + d0 + drow) * TT + t0 + c8 * 8) = v;
  }
}

// ---------------- K2: scores kernel: P = exp(sqrtD*QK^T + mask), l = rowsum.
// QBLK=64, 8 waves (rg, kg), KV-split (h), 32 strips of 32 keys each.
// Lean regs (no O accumulator) -> launch_bounds(512,4) -> 2 blocks/CU.
// K double-buffered 2x32KB via glds issued at strip TOP (hidden a full strip).
// P written [q][k] bf16 via Ps-LDS bounce (64B/row coalesced stores).
__global__ __launch_bounds__(512, 4) void k_score(
    const short* __restrict__ Qb, const short* __restrict__ Kb,
    const float* __restrict__ mask, short* __restrict__ Pq, float* __restrict__ Lh)
{
  __shared__ short Ks[2][32 * 512];  // 2 x 32KB
  __shared__ short Ps[64 * 32];      // 4KB, XOR-swizzled
  __shared__ float ls[4][2][16];
  const int b = blockIdx.x;          // batch on x => XCD-pinned
  const int q0 = blockIdx.y * 64;
  const int h = blockIdx.z;          // key half
  const int t = threadIdx.x;
  const int lane = t & 63;
  const int w = t >> 6;              // 0..7
  const int rg = w >> 1, kg = w & 1;
  const int l15 = lane & 15, l4 = lane >> 4;
  const int lo16 = lane * 16;

  const char* __restrict__ Kbase = (const char*)(Kb + (size_t)b * TT * DD);
  const float* __restrict__ Mbase = mask + ((size_t)b * TT + q0) * TT;

  // hoist Q fragments: 16 rows (rg group), full D=512 (64 VGPR)
  bv8 qf[16];
  #pragma unroll
  for (int kk = 0; kk < 16; ++kk)
    qf[kk] = *(const bv8*)(Qb + ((size_t)b * TT + q0 + rg * 16 + l15) * DD + kk * 32 + l4 * 8);

  float rsum[4] = {0.f, 0.f, 0.f, 0.f};
  float mko[4], mkn[4];

  // prologue: glds K(first strip) -> buf0; wave w owns rows [4w, 4w+4)
  {
    const char* Kstrip = Kbase + (size_t)(h * 32) * 32768;
    #pragma unroll
    for (int i = 0; i < 4; ++i) {
      int row = w * 4 + i;
      gld_lds16(Kstrip + row * 1024 + (lo16 ^ ((row & 7) << 4)), &Ks[0][row * 512]);
    }
  }
  __builtin_amdgcn_sched_barrier(0);
  #pragma unroll
  for (int r = 0; r < 4; ++r)
    mko[r] = Mbase[(size_t)(rg * 16 + l4 * 4 + r) * TT + h * 1024 + kg * 16 + l15];
  asm volatile("s_waitcnt vmcnt(4) lgkmcnt(0)\n\ts_barrier" ::: "memory");

  for (int j = 0; j < 32; ++j) {
    const int nt = h * 32 + j;
    const int ntn = h * 32 + ((j + 1) & 31);
    const int buf = j & 1;

    // ---- glds K(t+1) -> other buffer at strip TOP (retires at next bar)
    {
      const char* Kstrip = Kbase + (size_t)ntn * 32768;
      #pragma unroll
      for (int i = 0; i < 4; ++i) {
        int row = w * 4 + i;
        gld_lds16(Kstrip + row * 1024 + (lo16 ^ ((row & 7) << 4)), &Ks[buf ^ 1][row * 512]);
      }
    }
    __builtin_amdgcn_sched_barrier(0);

    // ---- QK^T: 16x16 tile per wave, K=512, 4 independent chains
    const int krow = kg * 16 + l15;
    const int ksw = (krow & 7) << 4;
    const char* KsR = (const char*)Ks[buf];
    fv4 s0 = {}, s1 = {}, s2 = {}, s3 = {};
    __builtin_amdgcn_s_setprio(1);
    #pragma unroll
    for (int kk = 0; kk < 16; kk += 4) {
      bv8 kf0 = *(const bv8*)(KsR + krow * 1024 + (((kk + 0) * 64 + l4 * 16) ^ ksw));
      bv8 kf1 = *(const bv8*)(KsR + krow * 1024 + (((kk + 1) * 64 + l4 * 16) ^ ksw));
      bv8 kf2 = *(const bv8*)(KsR + krow * 1024 + (((kk + 2) * 64 + l4 * 16) ^ ksw));
      bv8 kf3 = *(const bv8*)(KsR + krow * 1024 + (((kk + 3) * 64 + l4 * 16) ^ ksw));
      s0 = __builtin_amdgcn_mfma_f32_16x16x32_bf16(qf[kk + 0], kf0, s0, 0, 0, 0);
      s1 = __builtin_amdgcn_mfma_f32_16x16x32_bf16(qf[kk + 1], kf1, s1, 0, 0, 0);
      s2 = __builtin_amdgcn_mfma_f32_16x16x32_bf16(qf[kk + 2], kf2, s2, 0, 0, 0);
      s3 = __builtin_amdgcn_mfma_f32_16x16x32_bf16(qf[kk + 3], kf3, s3, 0, 0, 0);
    }
    __builtin_amdgcn_s_setprio(0);
    fv4 sa = (s0 + s1) + (s2 + s3);

    // ---- epilogue: scale + mask + exp -> Ps (swizzled), partial row sums
    #pragma unroll
    for (int r = 0; r < 4; ++r) {
      int row = rg * 16 + l4 * 4 + r;
      float sx = sa[r] * SQRTD + mko[r];
      float pv = __expf(sx);
      short pb = f2bf(pv);
      rsum[r] += bf2f(pb);
      *((short*)((char*)Ps + ((row * 64 + (kg * 16 + l15) * 2) ^ ((row & 7) << 4)))) = pb;
    }

    // bar1: Ps visible to all waves. No vmcnt drain (glds stays in flight).
    asm volatile("s_waitcnt lgkmcnt(0)\n\ts_barrier" ::: "memory");

    // ---- P store: wave w reads Ps rows [8w, 8w+8), writes Pq[q][k] bf16.
    // lane -> (row = 8w + lane>>3, 8B chunk = lane&7): 64B coalesced per row.
    {
      int prow = w * 8 + (lane >> 3);
      int chunk = lane & 7;
      iv2 pv2 = *(const iv2*)((const char*)Ps + ((prow * 64 + chunk * 8) ^ ((prow & 7) << 4)));
      *(iv2*)(Pq + ((size_t)b * TT + q0 + prow) * TT + (size_t)nt * 32 + chunk * 4) = pv2;
    }
    __builtin_amdgcn_sched_barrier(0);
    // ---- mask(t+1) (newest in FIFO; rides across bar2)
    #pragma unroll
    for (int r = 0; r < 4; ++r)
      mkn[r] = Mbase[(size_t)(rg * 16 + l4 * 4 + r) * TT + (size_t)ntn * 32 + kg * 16 + l15];
    #pragma unroll
    for (int r = 0; r < 4; ++r) mko[r] = mkn[r];

    // bar2: FIFO = [glds x4][Pstore x1][mask x4]; vmcnt(5) retires the glds
    // (K(t+1) ready), store+mask stay in flight. lgkm: Ps reads done.
    asm volatile("s_waitcnt vmcnt(5) lgkmcnt(0)\n\ts_barrier" ::: "memory");
  }

  // row-sum reduction over 16 key-residues, then across kg
  #pragma unroll
  for (int r = 0; r < 4; ++r) {
    float v = rsum[r];
    v += __shfl_xor(v, 1);
    v += __shfl_xor(v, 2);
    v += __shfl_xor(v, 4);
    v += __shfl_xor(v, 8);
    if (l15 == 0) ls[rg][kg][l4 * 4 + r] = v;
  }
  __syncthreads();
  if (w == 0 && l15 == 0) {
    #pragma unroll
    for (int mi = 0; mi < 4; ++mi)
      #pragma unroll
      for (int r = 0; r < 4; ++r)
        Lh[(size_t)h * BB * TT + (size_t)b * TT + q0 + mi * 16 + l4 * 4 + r] =
            ls[mi][0][l4 * 4 + r] + ls[mi][1][l4 * 4 + r];
  }
}

// ---------------- K3: O = (P @ Vt^T) / l  (bf16 in, f32 out)
// Per batch: M = T = 2048, N = D = 512, K = T = 2048. Tile 128x128, BK=64.
__global__ __launch_bounds__(256, 2) void k_pv(
    const short* __restrict__ P, const short* __restrict__ Vt,
    const float* __restrict__ Lh, float* __restrict__ Out)
{
  __shared__ short At[128 * 64];
  __shared__ short Bt[128 * 64];
  const int b = blockIdx.z;
  const int m0 = blockIdx.x * 128;
  const int n0 = blockIdx.y * 128;
  const int t = threadIdx.x;
  const int lane = t & 63;
  const int w = t >> 6;
  const int wr = (w >> 1) * 64, wc = (w & 1) * 64;
  fv4 acc[4][4] = {};
  for (int kt = 0; kt < TT; kt += 64) {
    #pragma unroll
    for (int j = 0; j < 4; ++j) {
      int f = j * 256 + t;
      int row = f >> 3, c8 = f & 7;
      int byte = (row * 128 + c8 * 16) ^ ((row & 7) << 4);
      bv8 va = *(const bv8*)(P + ((size_t)b * TT + m0 + row) * TT + kt + c8 * 8);
      *(bv8*)((char*)At + byte) = va;
      bv8 vb = *(const bv8*)(Vt + ((size_t)b * DD + n0 + row) * TT + kt + c8 * 8);
      *(bv8*)((char*)Bt + byte) = vb;
    }
    __syncthreads();
    #pragma unroll
    for (int ks = 0; ks < 2; ++ks) {
      bv8 af[4], bfr[4];
      #pragma unroll
      for (int i = 0; i < 4; ++i) {
        int ra = wr + i * 16 + (lane & 15);
        af[i] = *(bv8*)((char*)At + ((ra * 128 + ks * 64 + ((lane >> 4) * 16)) ^ ((ra & 7) << 4)));
        int rb = wc + i * 16 + (lane & 15);
        bfr[i] = *(bv8*)((char*)Bt + ((rb * 128 + ks * 64 + ((lane >> 4) * 16)) ^ ((rb & 7) << 4)));
      }
      #pragma unroll
      for (int mi = 0; mi < 4; ++mi)
        #pragma unroll
        for (int ni = 0; ni < 4; ++ni)
          acc[mi][ni] = __builtin_amdgcn_mfma_f32_16x16x32_bf16(af[mi], bfr[ni], acc[mi][ni], 0, 0, 0);
    }
    __syncthreads();
  }
  #pragma unroll
  for (int mi = 0; mi < 4; ++mi)
    #pragma unroll
    for (int r = 0; r < 4; ++r) {
      int gm = m0 + wr + mi * 16 + ((lane >> 4) << 2) + r;
      float inv = 1.0f / (Lh[(size_t)b * TT + gm] + Lh[(size_t)BB * TT + (size_t)b * TT + gm]);
      #pragma unroll
      for (int ni = 0; ni < 4; ++ni) {
        int gn = n0 + wc + ni * 16 + (lane & 15);
        Out[((size_t)b * TT + gm) * DD + gn] = acc[mi][ni][r] * inv;
      }
    }
}

extern "C" void kernel_launch(void* const* d_in, const int* in_sizes, int n_in,
                              void* d_out, int out_size, void* d_ws, size_t ws_size,
                              hipStream_t stream) {
  const float* ft_q = (const float*)d_in[0];
  const float* ft_k = (const float*)d_in[1];
  const float* ft_v = (const float*)d_in[2];
  const float* mask = (const float*)d_in[3];
  const float* Wq   = (const float*)d_in[4];
  const float* Wk   = (const float*)d_in[5];
  const float* Wv   = (const float*)d_in[6];
  float* Out = (float*)d_out;

  const size_t nBTD = (size_t)BB * TT * DD;   // 8,388,608
  const size_t nBTT = (size_t)BB * TT * TT;   // 33,554,432
  short* Qb = (short*)d_ws;
  short* Kb = Qb + nBTD;
  short* Vb = Kb + nBTD;
  short* Vt = Vb + nBTD;
  short* Pq = Vt + nBTD;
  float* Lh = (float*)(Pq + nBTT);            // [2][B][T]

  k_proj<<<dim3(128, 4, 3), 256, 0, stream>>>(ft_q, ft_k, ft_v, Wq, Wk, Wv, Qb, Kb, Vb);
  k_transpose<<<dim3(TT / 64, DD / 64, BB), 256, 0, stream>>>(Vb, Vt);
  k_score<<<dim3(BB, TT / 64, 2), 512, 0, stream>>>(Qb, Kb, mask, Pq, Lh);
  k_pv<<<dim3(TT / 128, DD / 128, BB), 256, 0, stream>>>(Pq, Vt, Lh, Out);
}

// Round 9
// 196.227 us; speedup vs baseline: 1.5164x; 1.5164x over previous
//
#include <hip/hip_runtime.h>
#include <hip/hip_bf16.h>

#define BB 8
#define TT 2048
#define DD 512
#define SQRTD 22.62741699796952f

typedef float fv4 __attribute__((ext_vector_type(4)));
typedef short bv8 __attribute__((ext_vector_type(8)));
typedef short bv4 __attribute__((ext_vector_type(4)));

__device__ __forceinline__ short f2bf(float f) {
  __hip_bfloat16 h = __float2bfloat16(f);
  return *reinterpret_cast<short*>(&h);
}

// ---------------- K1: fused projection GEMM: C = X @ W^T (f32 in, bf16 out)
__global__ __launch_bounds__(256, 2) void k_proj(
    const float* __restrict__ Xq, const float* __restrict__ Xk, const float* __restrict__ Xv,
    const float* __restrict__ Wq, const float* __restrict__ Wk, const float* __restrict__ Wv,
    short* __restrict__ Qb, short* __restrict__ Kb, short* __restrict__ Vb)
{
  __shared__ short At[128 * 64];
  __shared__ short Bt[128 * 64];
  const int z = blockIdx.z;
  const float* __restrict__ X = (z == 0) ? Xq : (z == 1) ? Xk : Xv;
  const float* __restrict__ W = (z == 0) ? Wq : (z == 1) ? Wk : Wv;
  short* __restrict__ C = (z == 0) ? Qb : (z == 1) ? Kb : Vb;
  const int m0 = blockIdx.x * 128;
  const int n0 = blockIdx.y * 128;
  const int t = threadIdx.x;
  const int lane = t & 63;
  const int w = t >> 6;
  const int wr = (w >> 1) * 64, wc = (w & 1) * 64;
  fv4 acc[4][4] = {};
  for (int kt = 0; kt < DD; kt += 64) {
    #pragma unroll
    for (int j = 0; j < 8; ++j) {
      int f = j * 256 + t;
      int row = f >> 4, c4 = f & 15;
      int byte = (row * 128 + c4 * 8) ^ ((row & 7) << 4);
      fv4 va = *(const fv4*)(X + (size_t)(m0 + row) * DD + kt + c4 * 4);
      bv4 ha;
      #pragma unroll
      for (int e = 0; e < 4; ++e) ha[e] = f2bf(va[e]);
      *(bv4*)((char*)At + byte) = ha;
      fv4 vb = *(const fv4*)(W + (size_t)(n0 + row) * DD + kt + c4 * 4);
      bv4 hb;
      #pragma unroll
      for (int e = 0; e < 4; ++e) hb[e] = f2bf(vb[e]);
      *(bv4*)((char*)Bt + byte) = hb;
    }
    __syncthreads();
    #pragma unroll
    for (int ks = 0; ks < 2; ++ks) {
      bv8 af[4], bfr[4];
      #pragma unroll
      for (int i = 0; i < 4; ++i) {
        int ra = wr + i * 16 + (lane & 15);
        af[i] = *(bv8*)((char*)At + ((ra * 128 + ks * 64 + ((lane >> 4) * 16)) ^ ((ra & 7) << 4)));
        int rb = wc + i * 16 + (lane & 15);
        bfr[i] = *(bv8*)((char*)Bt + ((rb * 128 + ks * 64 + ((lane >> 4) * 16)) ^ ((rb & 7) << 4)));
      }
      #pragma unroll
      for (int mi = 0; mi < 4; ++mi)
        #pragma unroll
        for (int ni = 0; ni < 4; ++ni)
          acc[mi][ni] = __builtin_amdgcn_mfma_f32_16x16x32_bf16(af[mi], bfr[ni], acc[mi][ni], 0, 0, 0);
    }
    __syncthreads();
  }
  #pragma unroll
  for (int mi = 0; mi < 4; ++mi)
    #pragma unroll
    for (int r = 0; r < 4; ++r) {
      int gm = m0 + wr + mi * 16 + ((lane >> 4) << 2) + r;
      #pragma unroll
      for (int ni = 0; ni < 4; ++ni) {
        int gn = n0 + wc + ni * 16 + (lane & 15);
        C[(size_t)gm * DD + gn] = f2bf(acc[mi][ni][r]);
      }
    }
}

// ---------------- K1b: transpose V (B,T,D) -> Vt (B,D,T), bf16
__global__ __launch_bounds__(256) void k_transpose(
    const short* __restrict__ Vb, short* __restrict__ Vt)
{
  __shared__ short tile[64][72];
  const int b = blockIdx.z;
  const int t0 = blockIdx.x * 64;
  const int d0 = blockIdx.y * 64;
  const int t = threadIdx.x;
  #pragma unroll
  for (int j = 0; j < 2; ++j) {
    int f = j * 256 + t;
    int row = f >> 3, c8 = f & 7;
    bv8 v = *(const bv8*)(Vb + ((size_t)b * TT + t0 + row) * DD + d0 + c8 * 8);
    *(bv8*)&tile[row][c8 * 8] = v;
  }
  __syncthreads();
  #pragma unroll
  for (int j = 0; j < 2; ++j) {
    int f = j * 256 + t;
    int drow = f >> 3, c8 = f & 7;
    bv8 v;
    #pragma unroll
    for (int e = 0; e < 8; ++e) v[e] = tile[c8 * 8 + e][drow];
    *(bv8*)(Vt + ((size_t)b * DD + d0 + drow) * TT + t0 + c8 * 8) = v;
  }
}

// ---------------- K2: S-GEMM with fused softmax-numerator epilogue.
// P[b][q][k] = exp(sqrtD * Q[b]K[b]^T + mask).  Tile 128x128, K = 512, 4 waves.
// Epilogue: scale+mask+exp -> LDS bounce (reuse staging tiles) -> coalesced store.
__global__ __launch_bounds__(256, 3) void k_sgemm(
    const short* __restrict__ Qb, const short* __restrict__ Kb,
    const float* __restrict__ mask, short* __restrict__ Pq)
{
  __shared__ __align__(16) short Sh[2][128 * 64];  // At | Bt ; epilogue: Ps[128][128]
  short* At = Sh[0];
  short* Bt = Sh[1];
  const int b = blockIdx.z;
  const int m0 = blockIdx.x * 128;   // q rows
  const int n0 = blockIdx.y * 128;   // k cols
  const int t = threadIdx.x;
  const int lane = t & 63;
  const int w = t >> 6;
  const int wr = (w >> 1) * 64, wc = (w & 1) * 64;
  const int l15 = lane & 15, l4 = lane >> 4;
  fv4 acc[4][4] = {};
  for (int kt = 0; kt < DD; kt += 64) {
    #pragma unroll
    for (int j = 0; j < 4; ++j) {
      int f = j * 256 + t;
      int row = f >> 3, c8 = f & 7;
      int byte = (row * 128 + c8 * 16) ^ ((row & 7) << 4);
      bv8 va = *(const bv8*)(Qb + ((size_t)b * TT + m0 + row) * DD + kt + c8 * 8);
      *(bv8*)((char*)At + byte) = va;
      bv8 vb = *(const bv8*)(Kb + ((size_t)b * TT + n0 + row) * DD + kt + c8 * 8);
      *(bv8*)((char*)Bt + byte) = vb;
    }
    __syncthreads();
    #pragma unroll
    for (int ks = 0; ks < 2; ++ks) {
      bv8 af[4], bfr[4];
      #pragma unroll
      for (int i = 0; i < 4; ++i) {
        int ra = wr + i * 16 + l15;
        af[i] = *(bv8*)((char*)At + ((ra * 128 + ks * 64 + (l4 * 16)) ^ ((ra & 7) << 4)));
        int rb = wc + i * 16 + l15;
        bfr[i] = *(bv8*)((char*)Bt + ((rb * 128 + ks * 64 + (l4 * 16)) ^ ((rb & 7) << 4)));
      }
      #pragma unroll
      for (int mi = 0; mi < 4; ++mi)
        #pragma unroll
        for (int ni = 0; ni < 4; ++ni)
          acc[mi][ni] = __builtin_amdgcn_mfma_f32_16x16x32_bf16(af[mi], bfr[ni], acc[mi][ni], 0, 0, 0);
    }
    __syncthreads();
  }
  // epilogue: scale + mask + exp -> Ps (swizzled 256B rows), then coalesced store
  short* Ps = &Sh[0][0];   // 128 rows x 256 B = 32 KB
  #pragma unroll
  for (int mi = 0; mi < 4; ++mi)
    #pragma unroll
    for (int r = 0; r < 4; ++r) {
      int row = wr + mi * 16 + (l4 << 2) + r;
      const float* mrow = mask + ((size_t)b * TT + m0 + row) * TT + n0;
      #pragma unroll
      for (int ni = 0; ni < 4; ++ni) {
        int col = wc + ni * 16 + l15;
        float sx = acc[mi][ni][r] * SQRTD + mrow[col];
        *(short*)((char*)Ps + ((row * 256 + col * 2) ^ ((row & 7) << 4))) = f2bf(__expf(sx));
      }
    }
  __syncthreads();
  #pragma unroll
  for (int c = 0; c < 8; ++c) {
    int f = c * 256 + t;
    int row = f >> 4, ch = f & 15;
    bv8 v = *(const bv8*)((const char*)Ps + ((row * 256 + ch * 16) ^ ((row & 7) << 4)));
    *(bv8*)(Pq + ((size_t)b * TT + m0 + row) * TT + n0 + ch * 8) = v;
  }
}

// ---------------- K3: O = (P @ Vt^T) / rowsum(P).  Tile 128x128, K = 2048.
// Row sums computed inline: acc_l[mi] = mfma(af[mi], ones, acc_l[mi]) gives the
// exact rowsum of the same bf16 P consumed by PV (C cols all identical).
__global__ __launch_bounds__(256, 3) void k_pv(
    const short* __restrict__ P, const short* __restrict__ Vt,
    float* __restrict__ Out)
{
  __shared__ __align__(16) short At[128 * 64];
  __shared__ __align__(16) short Bt[128 * 64];
  const int b = blockIdx.z;
  const int m0 = blockIdx.x * 128;
  const int n0 = blockIdx.y * 128;
  const int t = threadIdx.x;
  const int lane = t & 63;
  const int w = t >> 6;
  const int wr = (w >> 1) * 64, wc = (w & 1) * 64;
  const int l15 = lane & 15, l4 = lane >> 4;
  bv8 onesb;
  #pragma unroll
  for (int e = 0; e < 8; ++e) onesb[e] = (short)0x3F80;  // bf16 1.0
  fv4 acc[4][4] = {};
  fv4 acc_l[4] = {};
  for (int kt = 0; kt < TT; kt += 64) {
    #pragma unroll
    for (int j = 0; j < 4; ++j) {
      int f = j * 256 + t;
      int row = f >> 3, c8 = f & 7;
      int byte = (row * 128 + c8 * 16) ^ ((row & 7) << 4);
      bv8 va = *(const bv8*)(P + ((size_t)b * TT + m0 + row) * TT + kt + c8 * 8);
      *(bv8*)((char*)At + byte) = va;
      bv8 vb = *(const bv8*)(Vt + ((size_t)b * DD + n0 + row) * TT + kt + c8 * 8);
      *(bv8*)((char*)Bt + byte) = vb;
    }
    __syncthreads();
    #pragma unroll
    for (int ks = 0; ks < 2; ++ks) {
      bv8 af[4], bfr[4];
      #pragma unroll
      for (int i = 0; i < 4; ++i) {
        int ra = wr + i * 16 + l15;
        af[i] = *(bv8*)((char*)At + ((ra * 128 + ks * 64 + (l4 * 16)) ^ ((ra & 7) << 4)));
        int rb = wc + i * 16 + l15;
        bfr[i] = *(bv8*)((char*)Bt + ((rb * 128 + ks * 64 + (l4 * 16)) ^ ((rb & 7) << 4)));
      }
      #pragma unroll
      for (int mi = 0; mi < 4; ++mi) {
        acc_l[mi] = __builtin_amdgcn_mfma_f32_16x16x32_bf16(af[mi], onesb, acc_l[mi], 0, 0, 0);
        #pragma unroll
        for (int ni = 0; ni < 4; ++ni)
          acc[mi][ni] = __builtin_amdgcn_mfma_f32_16x16x32_bf16(af[mi], bfr[ni], acc[mi][ni], 0, 0, 0);
      }
    }
    __syncthreads();
  }
  #pragma unroll
  for (int mi = 0; mi < 4; ++mi)
    #pragma unroll
    for (int r = 0; r < 4; ++r) {
      int gm = m0 + wr + mi * 16 + (l4 << 2) + r;
      float inv = 1.0f / acc_l[mi][r];
      #pragma unroll
      for (int ni = 0; ni < 4; ++ni) {
        int gn = n0 + wc + ni * 16 + l15;
        Out[((size_t)b * TT + gm) * DD + gn] = acc[mi][ni][r] * inv;
      }
    }
}

extern "C" void kernel_launch(void* const* d_in, const int* in_sizes, int n_in,
                              void* d_out, int out_size, void* d_ws, size_t ws_size,
                              hipStream_t stream) {
  const float* ft_q = (const float*)d_in[0];
  const float* ft_k = (const float*)d_in[1];
  const float* ft_v = (const float*)d_in[2];
  const float* mask = (const float*)d_in[3];
  const float* Wq   = (const float*)d_in[4];
  const float* Wk   = (const float*)d_in[5];
  const float* Wv   = (const float*)d_in[6];
  float* Out = (float*)d_out;

  const size_t nBTD = (size_t)BB * TT * DD;   // 8,388,608
  const size_t nBTT = (size_t)BB * TT * TT;   // 33,554,432
  short* Qb = (short*)d_ws;
  short* Kb = Qb + nBTD;
  short* Vb = Kb + nBTD;
  short* Vt = Vb + nBTD;
  short* Pq = Vt + nBTD;

  k_proj<<<dim3(128, 4, 3), 256, 0, stream>>>(ft_q, ft_k, ft_v, Wq, Wk, Wv, Qb, Kb, Vb);
  k_transpose<<<dim3(TT / 64, DD / 64, BB), 256, 0, stream>>>(Vb, Vt);
  k_sgemm<<<dim3(TT / 128, TT / 128, BB), 256, 0, stream>>>(Qb, Kb, mask, Pq);
  k_pv<<<dim3(TT / 128, DD / 128, BB), 256, 0, stream>>>(Pq, Vt, Out);
}

// Round 10
// 182.721 us; speedup vs baseline: 1.6285x; 1.0739x over previous
//
#include <hip/hip_runtime.h>
#include <hip/hip_bf16.h>

#define BB 8
#define TT 2048
#define DD 512
#define SQRTD 22.62741699796952f

typedef float fv4 __attribute__((ext_vector_type(4)));
typedef short bv8 __attribute__((ext_vector_type(8)));
typedef short bv4 __attribute__((ext_vector_type(4)));

__device__ __forceinline__ short f2bf(float f) {
  __hip_bfloat16 h = __float2bfloat16(f);
  return *reinterpret_cast<short*>(&h);
}

__device__ __forceinline__ void gld_lds16(const void* g, void* l) {
  __builtin_amdgcn_global_load_lds(
      (const __attribute__((address_space(1))) void*)g,
      (__attribute__((address_space(3))) void*)l, 16, 0, 0);
}

// ---------------- K0: cast W (f32 512x512 x3) -> bf16
__global__ __launch_bounds__(256) void k_castw(
    const float* __restrict__ Wq, const float* __restrict__ Wk,
    const float* __restrict__ Wv, short* __restrict__ Wb)
{
  const int z = blockIdx.y;
  const float* __restrict__ src = (z == 0) ? Wq : (z == 1) ? Wk : Wv;
  short* __restrict__ dst = Wb + (size_t)z * DD * DD;
  int i = blockIdx.x * 256 + threadIdx.x;          // 8 elems per thread
  fv4 a = ((const fv4*)src)[i * 2];
  fv4 b = ((const fv4*)src)[i * 2 + 1];
  bv8 h;
  #pragma unroll
  for (int e = 0; e < 4; ++e) { h[e] = f2bf(a[e]); h[4 + e] = f2bf(b[e]); }
  ((bv8*)dst)[i] = h;
}

// ---------------- K1: projection GEMM: C = X @ W^T (X f32, W bf16, C bf16)
// Tile 128m x 256n, BK=64, 512 thr / 8 waves (2M x 4N, wave = 64x64).
// W via global_load_lds (linear dest, inverse-swizzled source); X staged
// f32 -> cvt -> swizzled ds_write (read once per 256 output cols).
__global__ __launch_bounds__(512, 4) void k_proj2(
    const float* __restrict__ Xq, const float* __restrict__ Xk, const float* __restrict__ Xv,
    const short* __restrict__ Wb,
    short* __restrict__ Qb, short* __restrict__ Kb, short* __restrict__ Vb)
{
  __shared__ short Xs[128 * 64];   // 16 KB
  __shared__ short Ws[256 * 64];   // 32 KB
  const int z = blockIdx.z;
  const float* __restrict__ X = (z == 0) ? Xq : (z == 1) ? Xk : Xv;
  const short* __restrict__ W = Wb + (size_t)z * DD * DD;
  short* __restrict__ C = (z == 0) ? Qb : (z == 1) ? Kb : Vb;
  const int m0 = blockIdx.x * 128;
  const int n0 = blockIdx.y * 256;
  const int t = threadIdx.x;
  const int lane = t & 63;
  const int w = t >> 6;
  const int wr = (w >> 2) * 64, wc = (w & 3) * 64;
  const int l15 = lane & 15, l4 = lane >> 4;
  fv4 acc[4][4] = {};
  for (int kt = 0; kt < DD; kt += 64) {
    // W: async glds, linear dest; source slot pre-swizzled (c8 ^ (row&7))
    #pragma unroll
    for (int j = 0; j < 4; ++j) {
      int f = j * 512 + t;
      int row = f >> 3, c8 = f & 7;
      gld_lds16(W + (size_t)(n0 + row) * DD + kt + ((c8 ^ (row & 7)) << 3),
                Ws + (size_t)f * 8);
    }
    // X: f32 load + cvt + swizzled ds_write
    #pragma unroll
    for (int j = 0; j < 4; ++j) {
      int f = j * 512 + t;
      int row = f >> 4, c4 = f & 15;
      fv4 va = *(const fv4*)(X + (size_t)(m0 + row) * DD + kt + c4 * 4);
      bv4 ha;
      #pragma unroll
      for (int e = 0; e < 4; ++e) ha[e] = f2bf(va[e]);
      *(bv4*)((char*)Xs + ((row * 128 + c4 * 8) ^ ((row & 7) << 4))) = ha;
    }
    __syncthreads();
    #pragma unroll
    for (int ks = 0; ks < 2; ++ks) {
      bv8 af[4], bfr[4];
      #pragma unroll
      for (int i = 0; i < 4; ++i) {
        int ra = wr + i * 16 + l15;
        af[i] = *(bv8*)((char*)Xs + ((ra * 128 + ks * 64 + l4 * 16) ^ ((ra & 7) << 4)));
        int rb = wc + i * 16 + l15;
        bfr[i] = *(bv8*)((char*)Ws + ((rb * 128 + ks * 64 + l4 * 16) ^ ((rb & 7) << 4)));
      }
      #pragma unroll
      for (int mi = 0; mi < 4; ++mi)
        #pragma unroll
        for (int ni = 0; ni < 4; ++ni)
          acc[mi][ni] = __builtin_amdgcn_mfma_f32_16x16x32_bf16(af[mi], bfr[ni], acc[mi][ni], 0, 0, 0);
    }
    __syncthreads();
  }
  #pragma unroll
  for (int mi = 0; mi < 4; ++mi)
    #pragma unroll
    for (int r = 0; r < 4; ++r) {
      int gm = m0 + wr + mi * 16 + (l4 << 2) + r;
      #pragma unroll
      for (int ni = 0; ni < 4; ++ni) {
        int gn = n0 + wc + ni * 16 + l15;
        C[(size_t)gm * DD + gn] = f2bf(acc[mi][ni][r]);
      }
    }
}

// ---------------- K1b: transpose V (B,T,D) -> Vt (B,D,T), bf16
__global__ __launch_bounds__(256) void k_transpose(
    const short* __restrict__ Vb, short* __restrict__ Vt)
{
  __shared__ short tile[64][72];
  const int b = blockIdx.z;
  const int t0 = blockIdx.x * 64;
  const int d0 = blockIdx.y * 64;
  const int t = threadIdx.x;
  #pragma unroll
  for (int j = 0; j < 2; ++j) {
    int f = j * 256 + t;
    int row = f >> 3, c8 = f & 7;
    bv8 v = *(const bv8*)(Vb + ((size_t)b * TT + t0 + row) * DD + d0 + c8 * 8);
    *(bv8*)&tile[row][c8 * 8] = v;
  }
  __syncthreads();
  #pragma unroll
  for (int j = 0; j < 2; ++j) {
    int f = j * 256 + t;
    int drow = f >> 3, c8 = f & 7;
    bv8 v;
    #pragma unroll
    for (int e = 0; e < 8; ++e) v[e] = tile[c8 * 8 + e][drow];
    *(bv8*)(Vt + ((size_t)b * DD + d0 + drow) * TT + t0 + c8 * 8) = v;
  }
}

// ---------------- K2: S-GEMM with fused softmax-numerator epilogue.
// P[b][q][k] = exp(sqrtD * Q[b]K[b]^T + mask).  Tile 128x128, K = 512, 4 waves.
__global__ __launch_bounds__(256, 3) void k_sgemm(
    const short* __restrict__ Qb, const short* __restrict__ Kb,
    const float* __restrict__ mask, short* __restrict__ Pq)
{
  __shared__ __align__(16) short Sh[2][128 * 64];  // At | Bt ; epilogue: Ps
  short* At = Sh[0];
  short* Bt = Sh[1];
  const int b = blockIdx.z;
  const int m0 = blockIdx.x * 128;   // q rows
  const int n0 = blockIdx.y * 128;   // k cols
  const int t = threadIdx.x;
  const int lane = t & 63;
  const int w = t >> 6;
  const int wr = (w >> 1) * 64, wc = (w & 1) * 64;
  const int l15 = lane & 15, l4 = lane >> 4;
  fv4 acc[4][4] = {};
  for (int kt = 0; kt < DD; kt += 64) {
    #pragma unroll
    for (int j = 0; j < 4; ++j) {
      int f = j * 256 + t;
      int row = f >> 3, c8 = f & 7;
      int byte = (row * 128 + c8 * 16) ^ ((row & 7) << 4);
      bv8 va = *(const bv8*)(Qb + ((size_t)b * TT + m0 + row) * DD + kt + c8 * 8);
      *(bv8*)((char*)At + byte) = va;
      bv8 vb = *(const bv8*)(Kb + ((size_t)b * TT + n0 + row) * DD + kt + c8 * 8);
      *(bv8*)((char*)Bt + byte) = vb;
    }
    __syncthreads();
    #pragma unroll
    for (int ks = 0; ks < 2; ++ks) {
      bv8 af[4], bfr[4];
      #pragma unroll
      for (int i = 0; i < 4; ++i) {
        int ra = wr + i * 16 + l15;
        af[i] = *(bv8*)((char*)At + ((ra * 128 + ks * 64 + (l4 * 16)) ^ ((ra & 7) << 4)));
        int rb = wc + i * 16 + l15;
        bfr[i] = *(bv8*)((char*)Bt + ((rb * 128 + ks * 64 + (l4 * 16)) ^ ((rb & 7) << 4)));
      }
      #pragma unroll
      for (int mi = 0; mi < 4; ++mi)
        #pragma unroll
        for (int ni = 0; ni < 4; ++ni)
          acc[mi][ni] = __builtin_amdgcn_mfma_f32_16x16x32_bf16(af[mi], bfr[ni], acc[mi][ni], 0, 0, 0);
    }
    __syncthreads();
  }
  // epilogue: scale + mask + exp -> Ps (swizzled 256B rows), then coalesced store
  short* Ps = &Sh[0][0];   // 128 rows x 256 B = 32 KB
  #pragma unroll
  for (int mi = 0; mi < 4; ++mi)
    #pragma unroll
    for (int r = 0; r < 4; ++r) {
      int row = wr + mi * 16 + (l4 << 2) + r;
      const float* mrow = mask + ((size_t)b * TT + m0 + row) * TT + n0;
      #pragma unroll
      for (int ni = 0; ni < 4; ++ni) {
        int col = wc + ni * 16 + l15;
        float sx = acc[mi][ni][r] * SQRTD + mrow[col];
        *(short*)((char*)Ps + ((row * 256 + col * 2) ^ ((row & 7) << 4))) = f2bf(__expf(sx));
      }
    }
  __syncthreads();
  #pragma unroll
  for (int c = 0; c < 8; ++c) {
    int f = c * 256 + t;
    int row = f >> 4, ch = f & 15;
    bv8 v = *(const bv8*)((const char*)Ps + ((row * 256 + ch * 16) ^ ((row & 7) << 4)));
    *(bv8*)(Pq + ((size_t)b * TT + m0 + row) * TT + n0 + ch * 8) = v;
  }
}

// ---------------- K3: O = (P @ Vt^T) / rowsum(P).  Tile 128x128, K = 2048.
// Row sums inline: acc_l[mi] = mfma(af[mi], ones, acc_l[mi]).
__global__ __launch_bounds__(256, 3) void k_pv(
    const short* __restrict__ P, const short* __restrict__ Vt,
    float* __restrict__ Out)
{
  __shared__ __align__(16) short At[128 * 64];
  __shared__ __align__(16) short Bt[128 * 64];
  const int b = blockIdx.z;
  const int m0 = blockIdx.x * 128;
  const int n0 = blockIdx.y * 128;
  const int t = threadIdx.x;
  const int lane = t & 63;
  const int w = t >> 6;
  const int wr = (w >> 1) * 64, wc = (w & 1) * 64;
  const int l15 = lane & 15, l4 = lane >> 4;
  bv8 onesb;
  #pragma unroll
  for (int e = 0; e < 8; ++e) onesb[e] = (short)0x3F80;  // bf16 1.0
  fv4 acc[4][4] = {};
  fv4 acc_l[4] = {};
  for (int kt = 0; kt < TT; kt += 64) {
    #pragma unroll
    for (int j = 0; j < 4; ++j) {
      int f = j * 256 + t;
      int row = f >> 3, c8 = f & 7;
      int byte = (row * 128 + c8 * 16) ^ ((row & 7) << 4);
      bv8 va = *(const bv8*)(P + ((size_t)b * TT + m0 + row) * TT + kt + c8 * 8);
      *(bv8*)((char*)At + byte) = va;
      bv8 vb = *(const bv8*)(Vt + ((size_t)b * DD + n0 + row) * TT + kt + c8 * 8);
      *(bv8*)((char*)Bt + byte) = vb;
    }
    __syncthreads();
    #pragma unroll
    for (int ks = 0; ks < 2; ++ks) {
      bv8 af[4], bfr[4];
      #pragma unroll
      for (int i = 0; i < 4; ++i) {
        int ra = wr + i * 16 + l15;
        af[i] = *(bv8*)((char*)At + ((ra * 128 + ks * 64 + (l4 * 16)) ^ ((ra & 7) << 4)));
        int rb = wc + i * 16 + l15;
        bfr[i] = *(bv8*)((char*)Bt + ((rb * 128 + ks * 64 + (l4 * 16)) ^ ((rb & 7) << 4)));
      }
      #pragma unroll
      for (int mi = 0; mi < 4; ++mi) {
        acc_l[mi] = __builtin_amdgcn_mfma_f32_16x16x32_bf16(af[mi], onesb, acc_l[mi], 0, 0, 0);
        #pragma unroll
        for (int ni = 0; ni < 4; ++ni)
          acc[mi][ni] = __builtin_amdgcn_mfma_f32_16x16x32_bf16(af[mi], bfr[ni], acc[mi][ni], 0, 0, 0);
      }
    }
    __syncthreads();
  }
  #pragma unroll
  for (int mi = 0; mi < 4; ++mi)
    #pragma unroll
    for (int r = 0; r < 4; ++r) {
      int gm = m0 + wr + mi * 16 + (l4 << 2) + r;
      float inv = 1.0f / acc_l[mi][r];
      #pragma unroll
      for (int ni = 0; ni < 4; ++ni) {
        int gn = n0 + wc + ni * 16 + l15;
        Out[((size_t)b * TT + gm) * DD + gn] = acc[mi][ni][r] * inv;
      }
    }
}

extern "C" void kernel_launch(void* const* d_in, const int* in_sizes, int n_in,
                              void* d_out, int out_size, void* d_ws, size_t ws_size,
                              hipStream_t stream) {
  const float* ft_q = (const float*)d_in[0];
  const float* ft_k = (const float*)d_in[1];
  const float* ft_v = (const float*)d_in[2];
  const float* mask = (const float*)d_in[3];
  const float* Wq   = (const float*)d_in[4];
  const float* Wk   = (const float*)d_in[5];
  const float* Wv   = (const float*)d_in[6];
  float* Out = (float*)d_out;

  const size_t nBTD = (size_t)BB * TT * DD;   // 8,388,608
  const size_t nBTT = (size_t)BB * TT * TT;   // 33,554,432
  short* Qb = (short*)d_ws;
  short* Kb = Qb + nBTD;
  short* Vb = Kb + nBTD;
  short* Vt = Vb + nBTD;
  short* Pq = Vt + nBTD;
  short* Wb = Pq + nBTT;                      // 3 x 512 x 512 bf16

  k_castw<<<dim3(DD * DD / 8 / 256, 3), 256, 0, stream>>>(Wq, Wk, Wv, Wb);
  k_proj2<<<dim3(TT * BB / 128, DD / 256, 3), 512, 0, stream>>>(ft_q, ft_k, ft_v, Wb, Qb, Kb, Vb);
  k_transpose<<<dim3(TT / 64, DD / 64, BB), 256, 0, stream>>>(Vb, Vt);
  k_sgemm<<<dim3(TT / 128, TT / 128, BB), 256, 0, stream>>>(Qb, Kb, mask, Pq);
  k_pv<<<dim3(TT / 128, DD / 128, BB), 256, 0, stream>>>(Pq, Vt, Out);
}